// Round 2
// baseline (1440.253 us; speedup 1.0000x reference)
//
#include <hip/hip_runtime.h>
#include <cstdint>
#include <cstddef>

// Problem constants (from reference): N=S=8192, F=O=64, MAXM=10
#define NN 8192
#define SS 8192
#define FF 64
#define MAXM 10

typedef __attribute__((ext_vector_type(8))) short bf16x8;
typedef __attribute__((ext_vector_type(4))) float f32x4;

// Split fp32 into bf16 hi (bit-truncate) + bf16 lo (truncated residual).
// a ~= hi + lo with relative error ~2^-16.
__device__ __forceinline__ void splitf(float a, unsigned short& h, unsigned short& l) {
    unsigned u = __float_as_uint(a);
    unsigned hb = u & 0xffff0000u;
    h = (unsigned short)(hb >> 16);
    float r = a - __uint_as_float(hb);   // exact in fp32
    l = (unsigned short)(__float_as_uint(r) >> 16);
}

// ---------------------------------------------------------------------------
// k_prep: transpose+split x [8192,64] fp32 -> xT_hi/xT_lo [64][8192] bf16 bits
// ---------------------------------------------------------------------------
__global__ __launch_bounds__(256) void k_prep(const float* __restrict__ x,
                                              unsigned short* __restrict__ xh,
                                              unsigned short* __restrict__ xl) {
    __shared__ float tile[64][65];
    int b = blockIdx.x;              // 128 blocks x 64 rows
    int tr = threadIdx.x >> 6;       // 0..3
    int tc = threadIdx.x & 63;
#pragma unroll
    for (int rr = 0; rr < 16; ++rr) {
        int row = rr * 4 + tr;
        tile[row][tc] = x[(size_t)(b * 64 + row) * 64 + tc];
    }
    __syncthreads();
#pragma unroll
    for (int rr = 0; rr < 16; ++rr) {
        int c = rr * 4 + tr;         // feature/column index
        int k = tc;                  // node index within this block of 64
        float a = tile[k][c];
        unsigned short h, l;
        splitf(a, h, l);
        xh[(size_t)c * NN + b * 64 + k] = h;
        xl[(size_t)c * NN + b * 64 + k] = l;
    }
}

// ---------------------------------------------------------------------------
// k_gemm: accP += Lp@x, accN += Ln@x via split-bf16 MFMA (3 passes).
// grid (64 rowblocks, 16 kchunks, 2 matrices) = 2048 blocks = 8 blocks/CU,
// block 256 (4 waves), 64 VGPR -> 8 waves/SIMD = 100% occupancy cap.
// Each wave: 32 rows (two 16-row tiles) x all 64 cols, K-chunk 512.
// A-frag loaded fp32 from global (coalesced: lanes {l,l+16,l+32,l+48} form one
// 128B row segment), split to hi/lo in-register. Register double-buffer on A
// (prefetch next step) so load->use distance = one full MFMA step.
// HBM-bound target: 512 MB @ ~6 TB/s ~ 85 us.
// ---------------------------------------------------------------------------
#define KCH   512
#define NSTEP 16   // KCH/32

__device__ __forceinline__ void loadA(const float* __restrict__ ap0,
                                      const float* __restrict__ ap1,
                                      int ko, f32x4 av[2][2]) {
    av[0][0] = *(const f32x4*)(ap0 + ko);
    av[0][1] = *(const f32x4*)(ap0 + ko + 4);
    av[1][0] = *(const f32x4*)(ap1 + ko);
    av[1][1] = *(const f32x4*)(ap1 + ko + 4);
}

__device__ __forceinline__ void loadB(const unsigned short* __restrict__ bh0,
                                      const unsigned short* __restrict__ bl0,
                                      int ko, bf16x8 bh[4], bf16x8 bl[4]) {
#pragma unroll
    for (int n = 0; n < 4; ++n) {
        bh[n] = *(const bf16x8*)(bh0 + (size_t)n * (16 * NN) + ko);
        bl[n] = *(const bf16x8*)(bl0 + (size_t)n * (16 * NN) + ko);
    }
}

__device__ __forceinline__ void gstep(const f32x4 av[2][2],
                                      const bf16x8 bh[4], const bf16x8 bl[4],
                                      f32x4 c[2][4]) {
#pragma unroll
    for (int t = 0; t < 2; ++t) {
        bf16x8 ah, al;
#pragma unroll
        for (int jj = 0; jj < 8; ++jj) {
            float a = av[t][jj >> 2][jj & 3];
            unsigned u = __float_as_uint(a);
            unsigned hb = u & 0xffff0000u;
            float r = a - __uint_as_float(hb);
            ah[jj] = (short)(hb >> 16);
            al[jj] = (short)(__float_as_uint(r) >> 16);
        }
#pragma unroll
        for (int n = 0; n < 4; ++n) {
            c[t][n] = __builtin_amdgcn_mfma_f32_16x16x32_bf16(ah, bh[n], c[t][n], 0, 0, 0);
            c[t][n] = __builtin_amdgcn_mfma_f32_16x16x32_bf16(ah, bl[n], c[t][n], 0, 0, 0);
            c[t][n] = __builtin_amdgcn_mfma_f32_16x16x32_bf16(al, bh[n], c[t][n], 0, 0, 0);
        }
    }
}

__global__ __launch_bounds__(256, 8) void k_gemm(const float* __restrict__ Lp,
                                                 const float* __restrict__ Ln,
                                                 const unsigned short* __restrict__ xh,
                                                 const unsigned short* __restrict__ xl,
                                                 float* __restrict__ accP,
                                                 float* __restrict__ accN) {
    const int wave = threadIdx.x >> 6;
    const int lane = threadIdx.x & 63;
    const int l16 = lane & 15;
    const int l4 = lane >> 4;  // 0..3
    const float* A = blockIdx.z ? Ln : Lp;
    float* acc = blockIdx.z ? accN : accP;
    const int row0 = blockIdx.x * 128 + wave * 32;
    const int k0 = blockIdx.y * KCH;

    const float* ap0 = A + (size_t)(row0 + l16) * NN + k0 + l4 * 8;
    const float* ap1 = ap0 + (size_t)16 * NN;
    const unsigned short* bh0 = xh + (size_t)l16 * NN + k0 + l4 * 8;
    const unsigned short* bl0 = xl + (size_t)l16 * NN + k0 + l4 * 8;

    f32x4 c[2][4] = {};
    f32x4 avA[2][2], avB[2][2];   // named double buffers (static indexing only)
    bf16x8 bh[4], bl[4];

    loadA(ap0, ap1, 0, avA);
    for (int s = 0; s < NSTEP; s += 2) {
        loadB(bh0, bl0, s * 32, bh, bl);
        loadA(ap0, ap1, (s + 1) * 32, avB);      // prefetch next step's A
        gstep(avA, bh, bl, c);
        loadB(bh0, bl0, (s + 1) * 32, bh, bl);
        if (s + 2 < NSTEP) loadA(ap0, ap1, (s + 2) * 32, avA);  // prefetch
        gstep(avB, bh, bl, c);
    }

    // C/D layout (16x16x32): col = lane&15, row = (lane>>4)*4 + r  [m89-verified]
#pragma unroll
    for (int t = 0; t < 2; ++t)
#pragma unroll
        for (int n = 0; n < 4; ++n)
#pragma unroll
            for (int r = 0; r < 4; ++r) {
                int row = row0 + t * 16 + l4 * 4 + r;
                int col = n * 16 + l16;
                atomicAdd(&acc[(size_t)row * FF + col], c[t][n][r]);
            }
}

// ---------------------------------------------------------------------------
// k_scan: stream inc [N,S] (row-major), extract sparse structure:
// cnt[j] = #members of structure j, firstA[j] = min member row,
// members[j*MAXM + slot] = member rows (unordered).
// 4 float4 per thread, wave-interleaved so each load instruction is fully
// coalesced (256 lanes x 16B contiguous); 4 outstanding loads/thread.
// ---------------------------------------------------------------------------
__global__ __launch_bounds__(256) void k_scan(const float4* __restrict__ inc4,
                                              int* __restrict__ cnt,
                                              int* __restrict__ firstA,
                                              int* __restrict__ members) {
    size_t b = (size_t)blockIdx.x * 1024 + threadIdx.x;
    float4 v0 = inc4[b];
    float4 v1 = inc4[b + 256];
    float4 v2 = inc4[b + 512];
    float4 v3 = inc4[b + 768];
#pragma unroll
    for (int k = 0; k < 4; ++k) {
        float4 v = (k == 0) ? v0 : (k == 1) ? v1 : (k == 2) ? v2 : v3;
        size_t base = (b + (size_t)k * 256) * 4;
        int i = (int)(base >> 13);      // row (node), S=8192
        int j = (int)(base & (SS - 1)); // col (structure), multiple of 4
        float vv[4] = {v.x, v.y, v.z, v.w};
#pragma unroll
        for (int c = 0; c < 4; ++c) {
            if (vv[c] != 0.0f) {
                int slot = atomicAdd(&cnt[j + c], 1);
                if (slot < MAXM) members[(j + c) * MAXM + slot] = i;
                atomicMin(&firstA[j + c], i);
            }
        }
    }
}

// ---------------------------------------------------------------------------
// k_struct: per structure j (one wave each, lane = feature):
//   m = cnt[j]; valid iff m in {3,4,10};
//   t = tanh(m * x[first] - sum_members(x)); scatter K3*t to members via atomics
// ---------------------------------------------------------------------------
__global__ __launch_bounds__(256) void k_struct(const float* __restrict__ x,
                                                const int* __restrict__ cnt,
                                                const int* __restrict__ firstA,
                                                const int* __restrict__ members,
                                                float* __restrict__ out2) {
    int j = blockIdx.x * 4 + (threadIdx.x >> 6);
    int f = threadIdx.x & 63;
    int m = cnt[j];
    if (!(m == 3 || m == 4 || m == 10)) return;   // wave-uniform
    int fi = firstA[j];
    float xf = x[(size_t)fi * FF + f];
    float s = 0.0f;
    int mem[MAXM];
#pragma unroll
    for (int t = 0; t < MAXM; ++t)
        if (t < m) { mem[t] = members[j * MAXM + t]; s += x[(size_t)mem[t] * FF + f]; }
    float tv = tanhf((float)m * xf - s);
    float val = 0.05f * tv;                        // K3
#pragma unroll
    for (int t = 0; t < MAXM; ++t)
        if (t < m) atomicAdd(&out2[(size_t)mem[t] * FF + f], val);
}

// ---------------------------------------------------------------------------
// k_final: out = (K0*x + K1*sin(accP) + K2*sin(accN) + out2) @ W + bias
// ---------------------------------------------------------------------------
__global__ __launch_bounds__(256) void k_final(const float* __restrict__ x,
                                               const float* __restrict__ accP,
                                               const float* __restrict__ accN,
                                               const float* __restrict__ out2,
                                               const float* __restrict__ W,
                                               const float* __restrict__ bias,
                                               float* __restrict__ out) {
    __shared__ float Wl[64 * 64];
    __shared__ float vbuf[4][64];
    int tid = threadIdx.x;
#pragma unroll
    for (int i = tid; i < 4096; i += 256) Wl[i] = W[i];
    int r = tid >> 6, f = tid & 63;
    size_t row = (size_t)blockIdx.x * 4 + r;
    size_t idx = row * FF + f;
    float v = 0.5f * x[idx] + 0.05f * sinf(accP[idx]) - 0.05f * sinf(accN[idx]) + out2[idx];
    vbuf[r][f] = v;
    __syncthreads();
    float o = bias[f];
#pragma unroll
    for (int k = 0; k < 64; ++k) o += vbuf[r][k] * Wl[k * 64 + f];
    out[idx] = o;
}

// ---------------------------------------------------------------------------
extern "C" void kernel_launch(void* const* d_in, const int* in_sizes, int n_in,
                              void* d_out, int out_size, void* d_ws, size_t ws_size,
                              hipStream_t stream) {
    const float* x    = (const float*)d_in[0];  // [8192,64]
    const float* Lp   = (const float*)d_in[1];  // [8192,8192]
    const float* Ln   = (const float*)d_in[2];  // [8192,8192]
    const float* inc  = (const float*)d_in[3];  // [8192,8192]
    const float* W    = (const float*)d_in[4];  // [64,64]
    const float* bias = (const float*)d_in[5];  // [64]
    float* out = (float*)d_out;

    char* ws = (char*)d_ws;
    float* accP = (float*)(ws);                                   // 2 MB
    float* accN = (float*)(ws + (2u << 20));                      // 2 MB
    float* out2 = (float*)(ws + (4u << 20));                      // 2 MB
    int* cnt    = (int*)(ws + (6u << 20));                        // 32 KB
    int* firstA = (int*)(ws + (6u << 20) + 32768);                // 32 KB
    int* members= (int*)(ws + (6u << 20) + 65536);                // 320 KB
    unsigned short* xhv = (unsigned short*)(ws + (6u << 20) + 65536 + 327680); // 1 MB
    unsigned short* xlv = xhv + (size_t)NN * FF;                  // 1 MB

    // zero accP/accN/out2/cnt in one contiguous memset; firstA = big sentinel
    hipMemsetAsync(ws, 0, (6u << 20) + 32768, stream);
    hipMemsetAsync(firstA, 0x7f, 32768, stream);

    k_prep<<<128, 256, 0, stream>>>(x, xhv, xlv);
    k_gemm<<<dim3(64, 16, 2), 256, 0, stream>>>(Lp, Ln, xhv, xlv, accP, accN);
    k_scan<<<16384, 256, 0, stream>>>((const float4*)inc, cnt, firstA, members);
    k_struct<<<2048, 256, 0, stream>>>(x, cnt, firstA, members, out2);
    k_final<<<2048, 256, 0, stream>>>(x, accP, accN, out2, W, bias, out);
}

// Round 3
// 773.980 us; speedup vs baseline: 1.8608x; 1.8608x over previous
//
#include <hip/hip_runtime.h>
#include <cstdint>
#include <cstddef>

// Problem constants (from reference): N=S=8192, F=O=64, MAXM=10
#define NN 8192
#define SS 8192
#define FF 64
#define MAXM 10

typedef __attribute__((ext_vector_type(8))) short bf16x8;
typedef __attribute__((ext_vector_type(4))) float f32x4;

// Split fp32 into bf16 hi (bit-truncate) + bf16 lo (truncated residual).
// a ~= hi + lo with relative error ~2^-16.
__device__ __forceinline__ void splitf(float a, unsigned short& h, unsigned short& l) {
    unsigned u = __float_as_uint(a);
    unsigned hb = u & 0xffff0000u;
    h = (unsigned short)(hb >> 16);
    float r = a - __uint_as_float(hb);   // exact in fp32
    l = (unsigned short)(__float_as_uint(r) >> 16);
}

// ---------------------------------------------------------------------------
// k_prep: transpose+split x [8192,64] fp32 -> xT_hi/xT_lo [64][8192] bf16 bits
// ---------------------------------------------------------------------------
__global__ __launch_bounds__(256) void k_prep(const float* __restrict__ x,
                                              unsigned short* __restrict__ xh,
                                              unsigned short* __restrict__ xl) {
    __shared__ float tile[64][65];
    int b = blockIdx.x;              // 128 blocks x 64 rows
    int tr = threadIdx.x >> 6;       // 0..3
    int tc = threadIdx.x & 63;
#pragma unroll
    for (int rr = 0; rr < 16; ++rr) {
        int row = rr * 4 + tr;
        tile[row][tc] = x[(size_t)(b * 64 + row) * 64 + tc];
    }
    __syncthreads();
#pragma unroll
    for (int rr = 0; rr < 16; ++rr) {
        int c = rr * 4 + tr;         // feature/column index
        int k = tc;                  // node index within this block of 64
        float a = tile[k][c];
        unsigned short h, l;
        splitf(a, h, l);
        xh[(size_t)c * NN + b * 64 + k] = h;
        xl[(size_t)c * NN + b * 64 + k] = l;
    }
}

// ---------------------------------------------------------------------------
// k_gemm: accP += Lp@x, accN += Ln@x via split-bf16 MFMA (3 passes).
// grid (64 rowblocks, 16 kchunks, 2 matrices) = 2048 blocks = 8 blocks/CU.
// __launch_bounds__(256,4): VGPR cap 128, compiler uses ~64 (round-1 verified)
// -> HW can still run 8 waves/SIMD; occupancy limiter is now neither grid nor
// VGPR. (256,8) was tried and forced a 32-VGPR allocation -> 3 GB scratch
// spill traffic, 3.5x slower. DO NOT tighten the bound again.
// Each wave: 32 rows (two 16-row tiles) x all 64 cols, K-chunk 512.
// A-frag loaded fp32 from global (coalesced), split hi/lo in-register,
// register double-buffer on A. HBM-bound target: 512 MB @ ~6 TB/s ~ 85 us.
// ---------------------------------------------------------------------------
#define KCH   512
#define NSTEP 16   // KCH/32

__device__ __forceinline__ void loadA(const float* __restrict__ ap0,
                                      const float* __restrict__ ap1,
                                      int ko, f32x4 av[2][2]) {
    av[0][0] = *(const f32x4*)(ap0 + ko);
    av[0][1] = *(const f32x4*)(ap0 + ko + 4);
    av[1][0] = *(const f32x4*)(ap1 + ko);
    av[1][1] = *(const f32x4*)(ap1 + ko + 4);
}

__device__ __forceinline__ void loadB(const unsigned short* __restrict__ bh0,
                                      const unsigned short* __restrict__ bl0,
                                      int ko, bf16x8 bh[4], bf16x8 bl[4]) {
#pragma unroll
    for (int n = 0; n < 4; ++n) {
        bh[n] = *(const bf16x8*)(bh0 + (size_t)n * (16 * NN) + ko);
        bl[n] = *(const bf16x8*)(bl0 + (size_t)n * (16 * NN) + ko);
    }
}

__device__ __forceinline__ void gstep(const f32x4 av[2][2],
                                      const bf16x8 bh[4], const bf16x8 bl[4],
                                      f32x4 c[2][4]) {
#pragma unroll
    for (int t = 0; t < 2; ++t) {
        bf16x8 ah, al;
#pragma unroll
        for (int jj = 0; jj < 8; ++jj) {
            float a = av[t][jj >> 2][jj & 3];
            unsigned u = __float_as_uint(a);
            unsigned hb = u & 0xffff0000u;
            float r = a - __uint_as_float(hb);
            ah[jj] = (short)(hb >> 16);
            al[jj] = (short)(__float_as_uint(r) >> 16);
        }
#pragma unroll
        for (int n = 0; n < 4; ++n) {
            c[t][n] = __builtin_amdgcn_mfma_f32_16x16x32_bf16(ah, bh[n], c[t][n], 0, 0, 0);
            c[t][n] = __builtin_amdgcn_mfma_f32_16x16x32_bf16(ah, bl[n], c[t][n], 0, 0, 0);
            c[t][n] = __builtin_amdgcn_mfma_f32_16x16x32_bf16(al, bh[n], c[t][n], 0, 0, 0);
        }
    }
}

__global__ __launch_bounds__(256, 4) void k_gemm(const float* __restrict__ Lp,
                                                 const float* __restrict__ Ln,
                                                 const unsigned short* __restrict__ xh,
                                                 const unsigned short* __restrict__ xl,
                                                 float* __restrict__ accP,
                                                 float* __restrict__ accN) {
    const int wave = threadIdx.x >> 6;
    const int lane = threadIdx.x & 63;
    const int l16 = lane & 15;
    const int l4 = lane >> 4;  // 0..3
    const float* A = blockIdx.z ? Ln : Lp;
    float* acc = blockIdx.z ? accN : accP;
    const int row0 = blockIdx.x * 128 + wave * 32;
    const int k0 = blockIdx.y * KCH;

    const float* ap0 = A + (size_t)(row0 + l16) * NN + k0 + l4 * 8;
    const float* ap1 = ap0 + (size_t)16 * NN;
    const unsigned short* bh0 = xh + (size_t)l16 * NN + k0 + l4 * 8;
    const unsigned short* bl0 = xl + (size_t)l16 * NN + k0 + l4 * 8;

    f32x4 c[2][4] = {};
    f32x4 avA[2][2], avB[2][2];   // named double buffers (static indexing only)
    bf16x8 bh[4], bl[4];

    loadA(ap0, ap1, 0, avA);
    for (int s = 0; s < NSTEP; s += 2) {
        loadB(bh0, bl0, s * 32, bh, bl);
        loadA(ap0, ap1, (s + 1) * 32, avB);      // prefetch next step's A
        gstep(avA, bh, bl, c);
        loadB(bh0, bl0, (s + 1) * 32, bh, bl);
        if (s + 2 < NSTEP) loadA(ap0, ap1, (s + 2) * 32, avA);  // prefetch
        gstep(avB, bh, bl, c);
    }

    // C/D layout (16x16x32): col = lane&15, row = (lane>>4)*4 + r  [m89-verified]
#pragma unroll
    for (int t = 0; t < 2; ++t)
#pragma unroll
        for (int n = 0; n < 4; ++n)
#pragma unroll
            for (int r = 0; r < 4; ++r) {
                int row = row0 + t * 16 + l4 * 4 + r;
                int col = n * 16 + l16;
                atomicAdd(&acc[(size_t)row * FF + col], c[t][n][r]);
            }
}

// ---------------------------------------------------------------------------
// k_scan: stream inc [N,S] (row-major), extract sparse structure:
// cnt[j] = #members of structure j, firstA[j] = min member row,
// members[j*MAXM + slot] = member rows (unordered).
// 4 float4 per thread, wave-interleaved so each load instruction is fully
// coalesced; 4 outstanding loads/thread.
// ---------------------------------------------------------------------------
__global__ __launch_bounds__(256) void k_scan(const float4* __restrict__ inc4,
                                              int* __restrict__ cnt,
                                              int* __restrict__ firstA,
                                              int* __restrict__ members) {
    size_t b = (size_t)blockIdx.x * 1024 + threadIdx.x;
    float4 v0 = inc4[b];
    float4 v1 = inc4[b + 256];
    float4 v2 = inc4[b + 512];
    float4 v3 = inc4[b + 768];
#pragma unroll
    for (int k = 0; k < 4; ++k) {
        float4 v = (k == 0) ? v0 : (k == 1) ? v1 : (k == 2) ? v2 : v3;
        size_t base = (b + (size_t)k * 256) * 4;
        int i = (int)(base >> 13);      // row (node), S=8192
        int j = (int)(base & (SS - 1)); // col (structure), multiple of 4
        float vv[4] = {v.x, v.y, v.z, v.w};
#pragma unroll
        for (int c = 0; c < 4; ++c) {
            if (vv[c] != 0.0f) {
                int slot = atomicAdd(&cnt[j + c], 1);
                if (slot < MAXM) members[(j + c) * MAXM + slot] = i;
                atomicMin(&firstA[j + c], i);
            }
        }
    }
}

// ---------------------------------------------------------------------------
// k_struct: per structure j (one wave each, lane = feature):
//   m = cnt[j]; valid iff m in {3,4,10};
//   t = tanh(m * x[first] - sum_members(x)); scatter K3*t to members via atomics
// ---------------------------------------------------------------------------
__global__ __launch_bounds__(256) void k_struct(const float* __restrict__ x,
                                                const int* __restrict__ cnt,
                                                const int* __restrict__ firstA,
                                                const int* __restrict__ members,
                                                float* __restrict__ out2) {
    int j = blockIdx.x * 4 + (threadIdx.x >> 6);
    int f = threadIdx.x & 63;
    int m = cnt[j];
    if (!(m == 3 || m == 4 || m == 10)) return;   // wave-uniform
    int fi = firstA[j];
    float xf = x[(size_t)fi * FF + f];
    float s = 0.0f;
    int mem[MAXM];
#pragma unroll
    for (int t = 0; t < MAXM; ++t)
        if (t < m) { mem[t] = members[j * MAXM + t]; s += x[(size_t)mem[t] * FF + f]; }
    float tv = tanhf((float)m * xf - s);
    float val = 0.05f * tv;                        // K3
#pragma unroll
    for (int t = 0; t < MAXM; ++t)
        if (t < m) atomicAdd(&out2[(size_t)mem[t] * FF + f], val);
}

// ---------------------------------------------------------------------------
// k_final: out = (K0*x + K1*sin(accP) + K2*sin(accN) + out2) @ W + bias
// ---------------------------------------------------------------------------
__global__ __launch_bounds__(256) void k_final(const float* __restrict__ x,
                                               const float* __restrict__ accP,
                                               const float* __restrict__ accN,
                                               const float* __restrict__ out2,
                                               const float* __restrict__ W,
                                               const float* __restrict__ bias,
                                               float* __restrict__ out) {
    __shared__ float Wl[64 * 64];
    __shared__ float vbuf[4][64];
    int tid = threadIdx.x;
#pragma unroll
    for (int i = tid; i < 4096; i += 256) Wl[i] = W[i];
    int r = tid >> 6, f = tid & 63;
    size_t row = (size_t)blockIdx.x * 4 + r;
    size_t idx = row * FF + f;
    float v = 0.5f * x[idx] + 0.05f * sinf(accP[idx]) - 0.05f * sinf(accN[idx]) + out2[idx];
    vbuf[r][f] = v;
    __syncthreads();
    float o = bias[f];
#pragma unroll
    for (int k = 0; k < 64; ++k) o += vbuf[r][k] * Wl[k * 64 + f];
    out[idx] = o;
}

// ---------------------------------------------------------------------------
extern "C" void kernel_launch(void* const* d_in, const int* in_sizes, int n_in,
                              void* d_out, int out_size, void* d_ws, size_t ws_size,
                              hipStream_t stream) {
    const float* x    = (const float*)d_in[0];  // [8192,64]
    const float* Lp   = (const float*)d_in[1];  // [8192,8192]
    const float* Ln   = (const float*)d_in[2];  // [8192,8192]
    const float* inc  = (const float*)d_in[3];  // [8192,8192]
    const float* W    = (const float*)d_in[4];  // [64,64]
    const float* bias = (const float*)d_in[5];  // [64]
    float* out = (float*)d_out;

    char* ws = (char*)d_ws;
    float* accP = (float*)(ws);                                   // 2 MB
    float* accN = (float*)(ws + (2u << 20));                      // 2 MB
    float* out2 = (float*)(ws + (4u << 20));                      // 2 MB
    int* cnt    = (int*)(ws + (6u << 20));                        // 32 KB
    int* firstA = (int*)(ws + (6u << 20) + 32768);                // 32 KB
    int* members= (int*)(ws + (6u << 20) + 65536);                // 320 KB
    unsigned short* xhv = (unsigned short*)(ws + (6u << 20) + 65536 + 327680); // 1 MB
    unsigned short* xlv = xhv + (size_t)NN * FF;                  // 1 MB

    // zero accP/accN/out2/cnt in one contiguous memset; firstA = big sentinel
    hipMemsetAsync(ws, 0, (6u << 20) + 32768, stream);
    hipMemsetAsync(firstA, 0x7f, 32768, stream);

    k_prep<<<128, 256, 0, stream>>>(x, xhv, xlv);
    k_gemm<<<dim3(64, 16, 2), 256, 0, stream>>>(Lp, Ln, xhv, xlv, accP, accN);
    k_scan<<<16384, 256, 0, stream>>>((const float4*)inc, cnt, firstA, members);
    k_struct<<<2048, 256, 0, stream>>>(x, cnt, firstA, members, out2);
    k_final<<<2048, 256, 0, stream>>>(x, accP, accN, out2, W, bias, out);
}